// Round 1
// baseline (120.190 us; speedup 1.0000x reference)
//
#include <hip/hip_runtime.h>
#include <cstdint>

// VQ-VAE vector quantizer, MI355X (gfx950). Round 6.
// Evidence r5: halving the LDS floor (fp8, 16B chunks) moved 45->43.3us only;
// MfmaUtil 13.7 / VALU 16 / HBM 27% / conflicts 0 => 2-phase stage+vmcnt+barrier
// structure is the cost (m233: ~70% overhead), not any pipe.
// r6: invert dataflow -- B (emb8, 256KB fp8) lives in REGISTERS:
//  - 1024-thr block = 16 waves x 64 codes (64 VGPR/wave of B), 1 block/CU,
//    grid 256. All 1024 codes in-block -> argmin closes without cross-block merge.
//  - z streams via 4KB LDS tiles (16 rows fp8): 1 float4/thread -> cvt_pk ->
//    swizzled ds_write_b32; reads are conflict-free ds_read_b128.
//  - MFMA:ds_read = 32:4 per wave-tile (was 2:1). No global_load_lds =>
//    barrier is lgkmcnt(0)+s_barrier only (no vmcnt drain). 10 barriers total.
//  - merge/gather/out-write pipelined across tiles: merge tile t-1, store t-2;
//    full-row 1KB coalesced writes (fixes 55MB->34MB write amplification).
// Floors: MFMA 8.2us, HBM 10.6us; predict vq_main ~15us (was 43.3).

typedef float f32x4 __attribute__((ext_vector_type(4)));
typedef long  l2    __attribute__((ext_vector_type(2)));
typedef _Float16 f16;
typedef f16 f16x8 __attribute__((ext_vector_type(8)));

#define D_DIM 256
#define K_CODES 1024
#define BM3 128                     // rows per block (8 tiles of 16)

#define BAR() asm volatile("s_waitcnt lgkmcnt(0)\n\ts_barrier" ::: "memory")

__device__ __forceinline__ long pack_fp8x8(float x0, float x1, float x2, float x3,
                                           float x4, float x5, float x6, float x7) {
    int w0 = __builtin_amdgcn_cvt_pk_fp8_f32(x0, x1, 0, false);
    w0     = __builtin_amdgcn_cvt_pk_fp8_f32(x2, x3, w0, true);
    int w1 = __builtin_amdgcn_cvt_pk_fp8_f32(x4, x5, 0, false);
    w1     = __builtin_amdgcn_cvt_pk_fp8_f32(x6, x7, w1, true);
    int2 p = {w0, w1};
    return __builtin_bit_cast(long, p);
}

// ---- Prep (verified r5, unchanged): zero loss slot; emb -> fp8 (x1024) in
// fragment-slice-linear order (16 slices of 64 codes; chunk = ct*256 + t*64 +
// q*16 + m holds k-dims [t*64+q*8,+8) and [t*64+32+q*8,+8) of code
// sp*64+ct*16+m); eTe = 1024*||e||^2 fp32. grid 256 x 256.
__global__ __launch_bounds__(256) void vq_prep(const float* __restrict__ emb,
                                               char* __restrict__ emb8,
                                               float* __restrict__ eTe,
                                               float* __restrict__ loss_slot) {
    const int tid = threadIdx.x, wave = tid >> 6, lane = tid & 63;
    if (blockIdx.x == 0 && tid == 0) *loss_slot = 0.0f;

    if (blockIdx.x < 64) {
        int ch  = blockIdx.x * 256 + tid;     // 16384 chunks
        int sp  = ch >> 10;
        int rem = ch & 1023;
        int ct  = rem >> 8;
        int t   = (rem >> 6) & 3;
        int l   = rem & 63;
        int qq  = l >> 4, mm = l & 15;
        int code = sp * 64 + ct * 16 + mm;
        const float* p = emb + (size_t)code * D_DIM;
        int b0 = t * 64 + qq * 8;
        int b1 = b0 + 32;
        float4 v0 = *(const float4*)(p + b0);
        float4 v1 = *(const float4*)(p + b0 + 4);
        float4 v2 = *(const float4*)(p + b1);
        float4 v3 = *(const float4*)(p + b1 + 4);
        l2 out;
        out.x = pack_fp8x8(v0.x * 1024.f, v0.y * 1024.f, v0.z * 1024.f, v0.w * 1024.f,
                           v1.x * 1024.f, v1.y * 1024.f, v1.z * 1024.f, v1.w * 1024.f);
        out.y = pack_fp8x8(v2.x * 1024.f, v2.y * 1024.f, v2.z * 1024.f, v2.w * 1024.f,
                           v3.x * 1024.f, v3.y * 1024.f, v3.z * 1024.f, v3.w * 1024.f);
        *(l2*)(emb8 + (size_t)ch * 16) = out;
    }

    int code = blockIdx.x * 4 + wave;
    float4 v = ((const float4*)(emb + (size_t)code * D_DIM))[lane];
    float s = v.x * v.x + v.y * v.y + v.z * v.z + v.w * v.w;
    #pragma unroll
    for (int off = 32; off >= 1; off >>= 1) s += __shfl_down(s, off);
    if (lane == 0) eTe[code] = 1024.0f * s;
}

// ---- Main kernel: B-in-registers, z streamed through 4KB LDS tiles. -------
// Wave w owns codes [w*64, w*64+64): Bv[ct*4+t64] = 16B chunk
// (w*1024 + ct*256 + t64*64 + lane) of emb8 -- .x pairs MFMA k-step 2*t64,
// .y pairs 2*t64+1 (same per-lane k-range as the A fragment).
// A tile (16 rows fp8) in LDS, chunk ci = X*16 + (row ^ (X&7)), X = t64*4+q;
// 16B at ci holds dims {t64*64+q*8..+7} and {t64*64+32+q*8..+7} of row.
// XOR swizzle makes both the 64-lane b32 write and b128 read conflict-free.
__global__ __launch_bounds__(1024, 4) void vq_main3(const float* __restrict__ z,
                                                    const char* __restrict__ emb8,
                                                    const float* __restrict__ eTe,
                                                    const float* __restrict__ emb,
                                                    float* __restrict__ out,
                                                    float* __restrict__ loss_slot,
                                                    float loss_scale) {
    __shared__ __align__(16) char sA[2][4096];   // z-tile fp8, double-buffered
    __shared__ float s_bB[8][16][16];            // [tile][wave][row] best score
    __shared__ int   s_bI[8][16][16];            // [tile][wave][row] best code
    __shared__ float s_red[16];

    const int tid  = threadIdx.x;
    const int w    = tid >> 6;         // wave id == staged row-in-tile
    const int lane = tid & 63;
    const int m    = lane & 15;        // A row / B col (code) / C col
    const int q    = lane >> 4;        // k-group / C row-group

    // B fragments for this wave's 64 codes: 16 x 16B = 64 VGPR.
    l2 Bv[16];
    {
        const l2* bp = (const l2*)emb8 + (size_t)w * 1024 + lane;
        #pragma unroll
        for (int i = 0; i < 16; i++) Bv[i] = bp[i * 64];
    }
    float ete[4];
    #pragma unroll
    for (int ct = 0; ct < 4; ct++) ete[ct] = eTe[w * 64 + ct * 16 + m];

    // Writer offset (constant per thread): thread stages row w, dims lane*4..+3.
    const int t64w = lane >> 4;
    const int qw   = (lane >> 1) & 3;
    const int Xw   = t64w * 4 + qw;
    const int wr_off = (Xw * 16 + (w ^ (Xw & 7))) * 16
                     + ((lane >> 3) & 1) * 8 + (lane & 1) * 4;

    const float* zp = z + (size_t)blockIdx.x * (BM3 * D_DIM) + tid * 4;

    float zsq, lsum = 0.0f;
    {   // tile 0 stage
        float4 v0 = *(const float4*)zp;
        zsq = v0.x * v0.x + v0.y * v0.y + v0.z * v0.z + v0.w * v0.w;
        int p = __builtin_amdgcn_cvt_pk_fp8_f32(v0.x, v0.y, 0, false);
        p     = __builtin_amdgcn_cvt_pk_fp8_f32(v0.z, v0.w, p, true);
        *(int*)(sA[0] + wr_off) = p;
    }
    BAR();

    float4 pend_e = {0.f, 0.f, 0.f, 0.f};
    float* pend_addr = out;

    #pragma unroll 1
    for (int tl = 0; tl < 8; tl++) {
        // (a) store gathered output row for tile tl-2 (load had a full tile to land)
        if (tl >= 2) *(float4*)pend_addr = pend_e;

        // (b) merge tile tl-1 across the 16 waves; issue emb gather (consumed at tl+1)
        if (tl >= 1) {
            const int pl = tl - 1;
            float b  = s_bB[pl][lane & 15][w];
            int   bi = s_bI[pl][lane & 15][w];
            #pragma unroll
            for (int off = 8; off >= 1; off >>= 1) {
                float ob = __shfl_xor(b, off);
                int   oi = __shfl_xor(bi, off);
                if (ob < b || (ob == b && oi < bi)) { b = ob; bi = oi; }
            }
            if (lane == 0) lsum += b;
            const float* er = emb + (size_t)bi * D_DIM;
            pend_e    = *(const float4*)(er + lane * 4);
            pend_addr = out + ((size_t)blockIdx.x * BM3 + pl * 16 + w) * D_DIM + lane * 4;
        }

        // (c) prefetch next z tile (in flight across the MFMA block)
        float4 vnext;
        if (tl < 7) vnext = *(const float4*)(zp + (tl + 1) * (16 * D_DIM));

        // (d) compute tile tl: 4 ds_read_b128 -> 32 MFMAs
        const char* bufA = sA[tl & 1];
        f32x4 acc[4];
        #pragma unroll
        for (int ct = 0; ct < 4; ct++) acc[ct] = (f32x4){0.f, 0.f, 0.f, 0.f};
        #pragma unroll
        for (int t64 = 0; t64 < 4; t64++) {
            const int X = t64 * 4 + q;
            l2 aT = *(const l2*)(bufA + (size_t)((X * 16 + (m ^ (X & 7))) * 16));
            #pragma unroll
            for (int ct = 0; ct < 4; ct++) {
                acc[ct] = __builtin_amdgcn_mfma_f32_16x16x32_fp8_fp8(aT.x, Bv[ct * 4 + t64].x, acc[ct], 0, 0, 0);
                acc[ct] = __builtin_amdgcn_mfma_f32_16x16x32_fp8_fp8(aT.y, Bv[ct * 4 + t64].y, acc[ct], 0, 0, 0);
            }
        }

        // (e) scores + argmin over this wave's 64 codes; stash per-wave result
        float best[4]; int bidx[4];
        #pragma unroll
        for (int r = 0; r < 4; r++) { best[r] = __builtin_inff(); bidx[r] = 0; }
        #pragma unroll
        for (int ct = 0; ct < 4; ct++) {
            const int code = w * 64 + ct * 16 + m;
            const float e2 = ete[ct];
            #pragma unroll
            for (int r = 0; r < 4; r++) {
                float sc = fmaf(-2.0f, acc[ct][r], e2);
                if (sc < best[r]) { best[r] = sc; bidx[r] = code; }
            }
        }
        #pragma unroll
        for (int r = 0; r < 4; r++) {
            float b = best[r]; int bi = bidx[r];
            #pragma unroll
            for (int off = 8; off >= 1; off >>= 1) {
                float ob = __shfl_xor(b, off);
                int   oi = __shfl_xor(bi, off);
                if (ob < b || (ob == b && oi < bi)) { b = ob; bi = oi; }
            }
            if (m == 0) { s_bB[tl][w][q * 4 + r] = b; s_bI[tl][w][q * 4 + r] = bi; }
        }

        // (f) pack next z tile into the other buffer
        if (tl < 7) {
            zsq += vnext.x * vnext.x + vnext.y * vnext.y
                 + vnext.z * vnext.z + vnext.w * vnext.w;
            int p = __builtin_amdgcn_cvt_pk_fp8_f32(vnext.x, vnext.y, 0, false);
            p     = __builtin_amdgcn_cvt_pk_fp8_f32(vnext.z, vnext.w, p, true);
            *(int*)(sA[(tl + 1) & 1] + wr_off) = p;
        }
        BAR();
    }

    // drain pipeline: store tile 6's row, then merge+gather+store tile 7
    *(float4*)pend_addr = pend_e;
    {
        float b  = s_bB[7][lane & 15][w];
        int   bi = s_bI[7][lane & 15][w];
        #pragma unroll
        for (int off = 8; off >= 1; off >>= 1) {
            float ob = __shfl_xor(b, off);
            int   oi = __shfl_xor(bi, off);
            if (ob < b || (ob == b && oi < bi)) { b = ob; bi = oi; }
        }
        if (lane == 0) lsum += b;
        const float* er = emb + (size_t)bi * D_DIM;
        float4 e = *(const float4*)(er + lane * 4);
        *(float4*)(out + ((size_t)blockIdx.x * BM3 + 7 * 16 + w) * D_DIM + lane * 4) = e;
    }

    // loss: sum(z^2) + sum_rows(best)/1024, one atomic per block
    #pragma unroll
    for (int off = 32; off >= 1; off >>= 1) zsq += __shfl_down(zsq, off);
    if (lane == 0) s_red[w] = zsq + lsum * (1.0f / 1024.0f);
    BAR();
    if (w == 0 && lane < 16) {
        float ls = s_red[lane];
        ls += __shfl_xor(ls, 1); ls += __shfl_xor(ls, 2);
        ls += __shfl_xor(ls, 4); ls += __shfl_xor(ls, 8);
        if (lane == 0) atomicAdd(loss_slot, ls * loss_scale);
    }
}

// ---- Fallback (round-2 structure, verified) — only if ws too small. --------
__global__ __launch_bounds__(256) void vq_prep_fb(const float* __restrict__ emb,
                                                  float* __restrict__ eTe,
                                                  float* __restrict__ loss_slot) {
    if (blockIdx.x == 0 && threadIdx.x == 0) *loss_slot = 0.0f;
    if (!eTe) return;
    int gtid = blockIdx.x * 256 + threadIdx.x;
    int code = gtid >> 6;
    int lane = threadIdx.x & 63;
    if (code >= K_CODES) return;
    float4 v = ((const float4*)(emb + (size_t)code * D_DIM))[lane];
    float s = v.x * v.x + v.y * v.y + v.z * v.z + v.w * v.w;
    #pragma unroll
    for (int off = 32; off >= 1; off >>= 1) s += __shfl_down(s, off);
    if (lane == 0) eTe[code] = s;
}

__global__ __launch_bounds__(128) void vq_main_fb(const float* __restrict__ z,
                                                  const float* __restrict__ emb,
                                                  const float* __restrict__ eTe_g,
                                                  float* __restrict__ out,
                                                  float* __restrict__ loss_slot,
                                                  float loss_scale) {
    __shared__ __align__(16) f16 sE[128 * D_DIM];
    __shared__ float s_ete[128];
    __shared__ int   s_idx2[128];
    __shared__ float s_red2[2];

    const int tid  = threadIdx.x;
    const int wave = tid >> 6;
    const int lane = tid & 63;
    const int m    = lane & 15;
    const int q    = lane >> 4;
    const size_t row0 = (size_t)blockIdx.x * 128 + (size_t)wave * 64;

    f16x8 A[4][8];
    #pragma unroll
    for (int st = 0; st < 4; st++) {
        const float* zr = z + (row0 + st * 16 + m) * D_DIM;
        #pragma unroll
        for (int s = 0; s < 8; s++) {
            const float* p = zr + s * 32 + q * 8;
            float4 v0 = *(const float4*)p;
            float4 v1 = *(const float4*)(p + 4);
            f16x8 a = {(f16)v0.x, (f16)v0.y, (f16)v0.z, (f16)v0.w,
                       (f16)v1.x, (f16)v1.y, (f16)v1.z, (f16)v1.w};
            A[st][s] = a;
        }
    }
    float best[4][4]; int bidx[4][4];
    #pragma unroll
    for (int st = 0; st < 4; st++)
        #pragma unroll
        for (int r = 0; r < 4; r++) { best[st][r] = __builtin_inff(); bidx[st][r] = 0; }

    const f16x8* sE8 = (const f16x8*)sE;
    #pragma unroll 1
    for (int sp = 0; sp < 8; sp++) {
        __syncthreads();
        if (eTe_g) s_ete[tid] = 1024.0f * eTe_g[sp * 128 + tid];
        else {
            const float* p = emb + (size_t)(sp * 128 + tid) * D_DIM;
            float ss = 0.f;
            for (int j = 0; j < D_DIM / 4; j++) {
                float4 v = ((const float4*)p)[j];
                ss += v.x * v.x + v.y * v.y + v.z * v.z + v.w * v.w;
            }
            s_ete[tid] = 1024.0f * ss;
        }
        const float* ebase = emb + (size_t)sp * 128 * D_DIM;
        #pragma unroll 4
        for (int it = 0; it < 32; it++) {
            int ch = it * 128 + tid;
            int cc = ((ch >> 9) << 4) | (ch & 15);
            int gg = (ch >> 4) & 31;
            const float* p = ebase + cc * D_DIM + gg * 8;
            float4 v0 = *(const float4*)p;
            float4 v1 = *(const float4*)(p + 4);
            f16x8 h = {(f16)(v0.x * 1024.f), (f16)(v0.y * 1024.f),
                       (f16)(v0.z * 1024.f), (f16)(v0.w * 1024.f),
                       (f16)(v1.x * 1024.f), (f16)(v1.y * 1024.f),
                       (f16)(v1.z * 1024.f), (f16)(v1.w * 1024.f)};
            *(f16x8*)(sE + (size_t)ch * 8) = h;
        }
        __syncthreads();
        for (int ct = 0; ct < 8; ct++) {
            f32x4 acc[4];
            #pragma unroll
            for (int st = 0; st < 4; st++) acc[st] = (f32x4){0.f, 0.f, 0.f, 0.f};
            #pragma unroll
            for (int s = 0; s < 8; s++) {
                f16x8 bh = sE8[ct * 512 + s * 64 + lane];
                #pragma unroll
                for (int st = 0; st < 4; st++)
                    acc[st] = __builtin_amdgcn_mfma_f32_16x16x32_f16(A[st][s], bh, acc[st], 0, 0, 0);
            }
            int codeL = ct * 16 + m;
            float ete = s_ete[codeL];
            int code  = sp * 128 + codeL;
            #pragma unroll
            for (int st = 0; st < 4; st++)
                #pragma unroll
                for (int r = 0; r < 4; r++) {
                    float sc = fmaf(-2.0f, acc[st][r], ete);
                    if (sc < best[st][r]) { best[st][r] = sc; bidx[st][r] = code; }
                }
        }
    }
    #pragma unroll
    for (int st = 0; st < 4; st++)
        #pragma unroll
        for (int r = 0; r < 4; r++) {
            float b = best[st][r]; int bi = bidx[st][r];
            #pragma unroll
            for (int off = 8; off >= 1; off >>= 1) {
                float ob = __shfl_xor(b, off);
                int   oi = __shfl_xor(bi, off);
                if (ob < b || (ob == b && oi < bi)) { b = ob; bi = oi; }
            }
            if (m == 0) s_idx2[wave * 64 + st * 16 + q * 4 + r] = bi;
        }
    __syncthreads();
    float lsum = 0.f;
    #pragma unroll
    for (int st = 0; st < 4; st++) {
        int rl = wave * 64 + st * 16 + m;
        int idxv = s_idx2[rl];
        const float* er = emb + (size_t)idxv * D_DIM;
        float* orow = out + ((size_t)blockIdx.x * 128 + rl) * D_DIM;
        #pragma unroll
        for (int s = 0; s < 8; s++) {
            int dd = s * 32 + q * 8;
            float4 e0 = *(const float4*)(er + dd);
            float4 e1 = *(const float4*)(er + dd + 4);
            *(float4*)(orow + dd)     = e0;
            *(float4*)(orow + dd + 4) = e1;
            f16x8 a = A[st][s];
            float d0 = e0.x - (float)a[0], d1 = e0.y - (float)a[1];
            float d2 = e0.z - (float)a[2], d3 = e0.w - (float)a[3];
            float d4 = e1.x - (float)a[4], d5 = e1.y - (float)a[5];
            float d6 = e1.z - (float)a[6], d7 = e1.w - (float)a[7];
            lsum += d0*d0 + d1*d1 + d2*d2 + d3*d3 + d4*d4 + d5*d5 + d6*d6 + d7*d7;
        }
    }
    #pragma unroll
    for (int off = 32; off >= 1; off >>= 1) lsum += __shfl_down(lsum, off);
    if (lane == 0) s_red2[wave] = lsum;
    __syncthreads();
    if (tid == 0) atomicAdd(loss_slot, (s_red2[0] + s_red2[1]) * loss_scale);
}

extern "C" void kernel_launch(void* const* d_in, const int* in_sizes, int n_in,
                              void* d_out, int out_size, void* d_ws, size_t ws_size,
                              hipStream_t stream) {
    const float* z   = (const float*)d_in[0];
    const float* emb = (const float*)d_in[1];
    float* out = (float*)d_out;
    const int NROWS = in_sizes[0] / D_DIM;              // 32768
    float* loss_slot = out + (size_t)in_sizes[0];
    float loss_scale = 1.25f / (float)in_sizes[0];

    const size_t emb8_bytes = (size_t)K_CODES * D_DIM;  // 256 KB
    const size_t need = emb8_bytes + K_CODES * sizeof(float);

    if (ws_size >= need) {
        char*  emb8 = (char*)d_ws;
        float* eTe  = (float*)((char*)d_ws + emb8_bytes);
        vq_prep<<<256, 256, 0, stream>>>(emb, emb8, eTe, loss_slot);
        vq_main3<<<NROWS / BM3, 1024, 0, stream>>>(z, emb8, eTe, emb, out, loss_slot, loss_scale);
    } else {
        float* eTe = (ws_size >= K_CODES * sizeof(float)) ? (float*)d_ws : nullptr;
        vq_prep_fb<<<K_CODES / 4, 256, 0, stream>>>(emb, eTe, loss_slot);
        vq_main_fb<<<NROWS / 128, 128, 0, stream>>>(z, emb, eTe, out, loss_slot, loss_scale);
    }
}

// Round 2
// 113.748 us; speedup vs baseline: 1.0566x; 1.0566x over previous
//
#include <hip/hip_runtime.h>
#include <cstdint>

// VQ-VAE vector quantizer, MI355X (gfx950). Round 7.
// Evidence r3-r6: four structures (1/2/4/4 waves-per-SIMD, LDS-B vs reg-B,
// 8-16 barriers) ALL land 43-46us with MfmaUtil ~13%, VALU 16-27%, HBM <30%.
// Theory: barrier-lockstep convoy -- all waves do the same phase at once, each
// phase serializing on one per-CU resource (DS pipe: A-stage + 40 shuffles/
// wave/tile for per-tile argmin ~12-15us; MFMA pipe; VALU) with no overlap
// (m233 mechanism). r7 removes ALL in-loop coupling:
//  - wave = independent unit: 16 FIXED rows x all 1024 codes. argmin stays
//    in-lane across slices; ONE butterfly at wave end (was 40 shfl/tile).
//  - B streamed from L2 (emb8 256KB, L2-resident) into register double-buffer
//    Ba/Bb (16 x 1KB coalesced loads/slice); no LDS, no barriers, no staging.
//  - per slice: 16 loads (next) || 32 MFMA (cur) || 64 cmp-sel; slice time
//    ~1.3k cyc >> L2 latency -> loads always landed.
//  - epilogue per wave: butterfly once, broadcast idx, gather emb row (L2),
//    1KB coalesced out rows. One __syncthreads at end for loss only.
// Floors: MFMA 8.4us, HBM 10.6us, L2 <=15us. Predict vq_main 14-20us.
// If STILL ~45us: structure is exonerated -> environmental (clocks/harness).

typedef float f32x4 __attribute__((ext_vector_type(4)));
typedef long  l2    __attribute__((ext_vector_type(2)));
typedef _Float16 f16;
typedef f16 f16x8 __attribute__((ext_vector_type(8)));

#define D_DIM 256
#define K_CODES 1024

__device__ __forceinline__ long pack_fp8x8(float x0, float x1, float x2, float x3,
                                           float x4, float x5, float x6, float x7) {
    int w0 = __builtin_amdgcn_cvt_pk_fp8_f32(x0, x1, 0, false);
    w0     = __builtin_amdgcn_cvt_pk_fp8_f32(x2, x3, w0, true);
    int w1 = __builtin_amdgcn_cvt_pk_fp8_f32(x4, x5, 0, false);
    w1     = __builtin_amdgcn_cvt_pk_fp8_f32(x6, x7, w1, true);
    int2 p = {w0, w1};
    return __builtin_bit_cast(long, p);
}

// ---- Prep (verified r5/r6, unchanged): zero loss slot; emb -> fp8 (x1024) in
// fragment-slice-linear order (16 slices of 64 codes; chunk = ct*256 + t*64 +
// q*16 + m holds k-dims [t*64+q*8,+8) and [t*64+32+q*8,+8) of code
// sp*64+ct*16+m); eTe = 1024*||e||^2 fp32. grid 256 x 256.
__global__ __launch_bounds__(256) void vq_prep(const float* __restrict__ emb,
                                               char* __restrict__ emb8,
                                               float* __restrict__ eTe,
                                               float* __restrict__ loss_slot) {
    const int tid = threadIdx.x, wave = tid >> 6, lane = tid & 63;
    if (blockIdx.x == 0 && tid == 0) *loss_slot = 0.0f;

    if (blockIdx.x < 64) {
        int ch  = blockIdx.x * 256 + tid;     // 16384 chunks
        int sp  = ch >> 10;
        int rem = ch & 1023;
        int ct  = rem >> 8;
        int t   = (rem >> 6) & 3;
        int l   = rem & 63;
        int qq  = l >> 4, mm = l & 15;
        int code = sp * 64 + ct * 16 + mm;
        const float* p = emb + (size_t)code * D_DIM;
        int b0 = t * 64 + qq * 8;
        int b1 = b0 + 32;
        float4 v0 = *(const float4*)(p + b0);
        float4 v1 = *(const float4*)(p + b0 + 4);
        float4 v2 = *(const float4*)(p + b1);
        float4 v3 = *(const float4*)(p + b1 + 4);
        l2 out;
        out.x = pack_fp8x8(v0.x * 1024.f, v0.y * 1024.f, v0.z * 1024.f, v0.w * 1024.f,
                           v1.x * 1024.f, v1.y * 1024.f, v1.z * 1024.f, v1.w * 1024.f);
        out.y = pack_fp8x8(v2.x * 1024.f, v2.y * 1024.f, v2.z * 1024.f, v2.w * 1024.f,
                           v3.x * 1024.f, v3.y * 1024.f, v3.z * 1024.f, v3.w * 1024.f);
        *(l2*)(emb8 + (size_t)ch * 16) = out;
    }

    // eTe: one wave per code, 4 codes per block, pre-scaled by 1024.
    int code = blockIdx.x * 4 + wave;
    float4 v = ((const float4*)(emb + (size_t)code * D_DIM))[lane];
    float s = v.x * v.x + v.y * v.y + v.z * v.z + v.w * v.w;
    #pragma unroll
    for (int off = 32; off >= 1; off >>= 1) s += __shfl_down(s, off);
    if (lane == 0) eTe[code] = 1024.0f * s;
}

// ---- Main kernel: wave-independent, B register-double-buffered from L2. ----
__device__ __forceinline__ void loadB(l2 (&B)[16], const l2* __restrict__ gB,
                                      int sl, int lane) {
    const l2* p = gB + (size_t)sl * 1024 + lane;
    #pragma unroll
    for (int j = 0; j < 16; j++) B[j] = p[j * 64];   // 1KB coalesced each
}

__device__ __forceinline__ void computeSlice(const l2 (&B)[16], const long (&A8)[8],
                                             const float* __restrict__ eTe, int sl,
                                             int m, float (&best)[4], int (&bidx)[4]) {
    float ete[4];
    #pragma unroll
    for (int ct = 0; ct < 4; ct++) ete[ct] = eTe[sl * 64 + ct * 16 + m];

    f32x4 acc[4];
    #pragma unroll
    for (int ct = 0; ct < 4; ct++) acc[ct] = (f32x4){0.f, 0.f, 0.f, 0.f};

    __builtin_amdgcn_s_setprio(1);
    #pragma unroll
    for (int t = 0; t < 4; t++) {
        #pragma unroll
        for (int ct = 0; ct < 4; ct++) {
            acc[ct] = __builtin_amdgcn_mfma_f32_16x16x32_fp8_fp8(A8[2*t],   B[ct*4+t].x, acc[ct], 0, 0, 0);
            acc[ct] = __builtin_amdgcn_mfma_f32_16x16x32_fp8_fp8(A8[2*t+1], B[ct*4+t].y, acc[ct], 0, 0, 0);
        }
    }
    __builtin_amdgcn_s_setprio(0);

    #pragma unroll
    for (int ct = 0; ct < 4; ct++) {
        const int code = sl * 64 + ct * 16 + m;
        #pragma unroll
        for (int r = 0; r < 4; r++) {
            float sc = fmaf(-2.0f, acc[ct][r], ete[ct]);
            if (sc < best[r]) { best[r] = sc; bidx[r] = code; }
        }
    }
}

__global__ __launch_bounds__(256, 2) void vq_main4(const float* __restrict__ z,
                                                   const char* __restrict__ emb8,
                                                   const float* __restrict__ eTe,
                                                   const float* __restrict__ emb,
                                                   float* __restrict__ out,
                                                   float* __restrict__ loss_slot,
                                                   float loss_scale) {
    __shared__ float s_red[4];

    const int tid  = threadIdx.x;
    const int w    = tid >> 6;
    const int lane = tid & 63;
    const int m    = lane & 15;        // A row / B col (code) / C col
    const int q    = lane >> 4;        // k-group / C row-group
    const int gw   = blockIdx.x * 4 + w;       // global wave -> its 16 rows
    const size_t row0 = (size_t)gw * 16;

    const l2* gB = (const l2*)emb8;
    l2 Ba[16], Bb[16];
    loadB(Ba, gB, 0, lane);            // slice 0 in flight under A-pack

    // A fragments: this wave's 16 rows -> fp8 (verified r5/r6 layout):
    // lane (q,m) holds row m, k-dims [s*32+q*8, +8) per k-step s.
    long A8[8];
    float zsq = 0.f;
    {
        const float* zr = z + (row0 + m) * D_DIM;
        #pragma unroll
        for (int s = 0; s < 8; s++) {
            const float* p = zr + s * 32 + q * 8;
            float4 v0 = *(const float4*)p;
            float4 v1 = *(const float4*)(p + 4);
            zsq += v0.x * v0.x + v0.y * v0.y + v0.z * v0.z + v0.w * v0.w
                 + v1.x * v1.x + v1.y * v1.y + v1.z * v1.z + v1.w * v1.w;
            A8[s] = pack_fp8x8(v0.x, v0.y, v0.z, v0.w, v1.x, v1.y, v1.z, v1.w);
        }
    }
    loadB(Bb, gB, 1, lane);            // slice 1 in flight under slice 0 compute

    float best[4];
    int   bidx[4];
    #pragma unroll
    for (int r = 0; r < 4; r++) { best[r] = __builtin_inff(); bidx[r] = 0; }

    // 16 slices, register double-buffer, zero barriers/LDS/shuffles in loop.
    #pragma unroll 1
    for (int ii = 0; ii < 16; ii += 2) {
        computeSlice(Ba, A8, eTe, ii, m, best, bidx);
        if (ii + 2 < 16) loadB(Ba, gB, ii + 2, lane);
        computeSlice(Bb, A8, eTe, ii + 1, m, best, bidx);
        if (ii + 3 < 16) loadB(Bb, gB, ii + 3, lane);
    }

    // ONE cross-lane argmin per wave (xor-butterfly: all 16 lanes of each
    // q-group converge to the group's min; first-index tie-break).
    #pragma unroll
    for (int r = 0; r < 4; r++) {
        float b  = best[r];
        int   bi = bidx[r];
        #pragma unroll
        for (int off = 8; off >= 1; off >>= 1) {
            float ob = __shfl_xor(b, off);
            int   oi = __shfl_xor(bi, off);
            if (ob < b || (ob == b && oi < bi)) { b = ob; bi = oi; }
        }
        best[r] = b; bidx[r] = bi;     // uniform within each 16-lane q-group
    }

    // Epilogue per wave: broadcast idx of row (qq*4+r) from lane qq*16,
    // gather emb row (L2-hot, 1KB coalesced), write out row (1KB coalesced).
    float lsum = 0.f;
    float* orow0 = out + row0 * D_DIM + (size_t)lane * 4;
    #pragma unroll
    for (int row = 0; row < 16; row++) {
        const int r  = row & 3;
        const int qq = row >> 2;
        int   bi = __shfl(bidx[r], qq * 16);
        float b  = __shfl(best[r], qq * 16);
        lsum += b;                               // uniform across lanes
        float4 ev = *(const float4*)(emb + (size_t)bi * D_DIM + lane * 4);
        *(float4*)(orow0 + (size_t)row * D_DIM) = ev;
    }

    // loss: sum(z^2) over the wave's rows + sum(best)/1024.
    #pragma unroll
    for (int off = 32; off >= 1; off >>= 1) zsq += __shfl_down(zsq, off);
    if (lane == 0) s_red[w] = zsq + lsum * (1.0f / 1024.0f);
    __syncthreads();
    if (tid == 0)
        atomicAdd(loss_slot, (s_red[0] + s_red[1] + s_red[2] + s_red[3]) * loss_scale);
}

// ---- Fallback (round-2 structure, verified) — only if ws too small. --------
__global__ __launch_bounds__(256) void vq_prep_fb(const float* __restrict__ emb,
                                                  float* __restrict__ eTe,
                                                  float* __restrict__ loss_slot) {
    if (blockIdx.x == 0 && threadIdx.x == 0) *loss_slot = 0.0f;
    if (!eTe) return;
    int gtid = blockIdx.x * 256 + threadIdx.x;
    int code = gtid >> 6;
    int lane = threadIdx.x & 63;
    if (code >= K_CODES) return;
    float4 v = ((const float4*)(emb + (size_t)code * D_DIM))[lane];
    float s = v.x * v.x + v.y * v.y + v.z * v.z + v.w * v.w;
    #pragma unroll
    for (int off = 32; off >= 1; off >>= 1) s += __shfl_down(s, off);
    if (lane == 0) eTe[code] = s;
}

__global__ __launch_bounds__(128) void vq_main_fb(const float* __restrict__ z,
                                                  const float* __restrict__ emb,
                                                  const float* __restrict__ eTe_g,
                                                  float* __restrict__ out,
                                                  float* __restrict__ loss_slot,
                                                  float loss_scale) {
    __shared__ __align__(16) f16 sE[128 * D_DIM];
    __shared__ float s_ete[128];
    __shared__ int   s_idx2[128];
    __shared__ float s_red2[2];

    const int tid  = threadIdx.x;
    const int wave = tid >> 6;
    const int lane = tid & 63;
    const int m    = lane & 15;
    const int q    = lane >> 4;
    const size_t row0 = (size_t)blockIdx.x * 128 + (size_t)wave * 64;

    f16x8 A[4][8];
    #pragma unroll
    for (int st = 0; st < 4; st++) {
        const float* zr = z + (row0 + st * 16 + m) * D_DIM;
        #pragma unroll
        for (int s = 0; s < 8; s++) {
            const float* p = zr + s * 32 + q * 8;
            float4 v0 = *(const float4*)p;
            float4 v1 = *(const float4*)(p + 4);
            f16x8 a = {(f16)v0.x, (f16)v0.y, (f16)v0.z, (f16)v0.w,
                       (f16)v1.x, (f16)v1.y, (f16)v1.z, (f16)v1.w};
            A[st][s] = a;
        }
    }
    float best[4][4]; int bidx[4][4];
    #pragma unroll
    for (int st = 0; st < 4; st++)
        #pragma unroll
        for (int r = 0; r < 4; r++) { best[st][r] = __builtin_inff(); bidx[st][r] = 0; }

    const f16x8* sE8 = (const f16x8*)sE;
    #pragma unroll 1
    for (int sp = 0; sp < 8; sp++) {
        __syncthreads();
        if (eTe_g) s_ete[tid] = 1024.0f * eTe_g[sp * 128 + tid];
        else {
            const float* p = emb + (size_t)(sp * 128 + tid) * D_DIM;
            float ss = 0.f;
            for (int j = 0; j < D_DIM / 4; j++) {
                float4 v = ((const float4*)p)[j];
                ss += v.x * v.x + v.y * v.y + v.z * v.z + v.w * v.w;
            }
            s_ete[tid] = 1024.0f * ss;
        }
        const float* ebase = emb + (size_t)sp * 128 * D_DIM;
        #pragma unroll 4
        for (int it = 0; it < 32; it++) {
            int ch = it * 128 + tid;
            int cc = ((ch >> 9) << 4) | (ch & 15);
            int gg = (ch >> 4) & 31;
            const float* p = ebase + cc * D_DIM + gg * 8;
            float4 v0 = *(const float4*)p;
            float4 v1 = *(const float4*)(p + 4);
            f16x8 h = {(f16)(v0.x * 1024.f), (f16)(v0.y * 1024.f),
                       (f16)(v0.z * 1024.f), (f16)(v0.w * 1024.f),
                       (f16)(v1.x * 1024.f), (f16)(v1.y * 1024.f),
                       (f16)(v1.z * 1024.f), (f16)(v1.w * 1024.f)};
            *(f16x8*)(sE + (size_t)ch * 8) = h;
        }
        __syncthreads();
        for (int ct = 0; ct < 8; ct++) {
            f32x4 acc[4];
            #pragma unroll
            for (int st = 0; st < 4; st++) acc[st] = (f32x4){0.f, 0.f, 0.f, 0.f};
            #pragma unroll
            for (int s = 0; s < 8; s++) {
                f16x8 bh = sE8[ct * 512 + s * 64 + lane];
                #pragma unroll
                for (int st = 0; st < 4; st++)
                    acc[st] = __builtin_amdgcn_mfma_f32_16x16x32_f16(A[st][s], bh, acc[st], 0, 0, 0);
            }
            int codeL = ct * 16 + m;
            float ete = s_ete[codeL];
            int code  = sp * 128 + codeL;
            #pragma unroll
            for (int st = 0; st < 4; st++)
                #pragma unroll
                for (int r = 0; r < 4; r++) {
                    float sc = fmaf(-2.0f, acc[st][r], ete);
                    if (sc < best[st][r]) { best[st][r] = sc; bidx[st][r] = code; }
                }
        }
    }
    #pragma unroll
    for (int st = 0; st < 4; st++)
        #pragma unroll
        for (int r = 0; r < 4; r++) {
            float b = best[st][r]; int bi = bidx[st][r];
            #pragma unroll
            for (int off = 8; off >= 1; off >>= 1) {
                float ob = __shfl_xor(b, off);
                int   oi = __shfl_xor(bi, off);
                if (ob < b || (ob == b && oi < bi)) { b = ob; bi = oi; }
            }
            if (m == 0) s_idx2[wave * 64 + st * 16 + q * 4 + r] = bi;
        }
    __syncthreads();
    float lsum = 0.f;
    #pragma unroll
    for (int st = 0; st < 4; st++) {
        int rl = wave * 64 + st * 16 + m;
        int idxv = s_idx2[rl];
        const float* er = emb + (size_t)idxv * D_DIM;
        float* orow = out + ((size_t)blockIdx.x * 128 + rl) * D_DIM;
        #pragma unroll
        for (int s = 0; s < 8; s++) {
            int dd = s * 32 + q * 8;
            float4 e0 = *(const float4*)(er + dd);
            float4 e1 = *(const float4*)(er + dd + 4);
            *(float4*)(orow + dd)     = e0;
            *(float4*)(orow + dd + 4) = e1;
            f16x8 a = A[st][s];
            float d0 = e0.x - (float)a[0], d1 = e0.y - (float)a[1];
            float d2 = e0.z - (float)a[2], d3 = e0.w - (float)a[3];
            float d4 = e1.x - (float)a[4], d5 = e1.y - (float)a[5];
            float d6 = e1.z - (float)a[6], d7 = e1.w - (float)a[7];
            lsum += d0*d0 + d1*d1 + d2*d2 + d3*d3 + d4*d4 + d5*d5 + d6*d6 + d7*d7;
        }
    }
    #pragma unroll
    for (int off = 32; off >= 1; off >>= 1) lsum += __shfl_down(lsum, off);
    if (lane == 0) s_red2[wave] = lsum;
    __syncthreads();
    if (tid == 0) atomicAdd(loss_slot, (s_red2[0] + s_red2[1]) * loss_scale);
}

extern "C" void kernel_launch(void* const* d_in, const int* in_sizes, int n_in,
                              void* d_out, int out_size, void* d_ws, size_t ws_size,
                              hipStream_t stream) {
    const float* z   = (const float*)d_in[0];
    const float* emb = (const float*)d_in[1];
    float* out = (float*)d_out;
    const int NROWS = in_sizes[0] / D_DIM;              // 32768
    float* loss_slot = out + (size_t)in_sizes[0];
    float loss_scale = 1.25f / (float)in_sizes[0];

    const size_t emb8_bytes = (size_t)K_CODES * D_DIM;  // 256 KB
    const size_t need = emb8_bytes + K_CODES * sizeof(float);

    if (ws_size >= need) {
        char*  emb8 = (char*)d_ws;
        float* eTe  = (float*)((char*)d_ws + emb8_bytes);
        vq_prep<<<256, 256, 0, stream>>>(emb, emb8, eTe, loss_slot);
        vq_main4<<<NROWS / 64, 256, 0, stream>>>(z, emb8, eTe, emb, out, loss_slot, loss_scale);
    } else {
        float* eTe = (ws_size >= K_CODES * sizeof(float)) ? (float*)d_ws : nullptr;
        vq_prep_fb<<<K_CODES / 4, 256, 0, stream>>>(emb, eTe, loss_slot);
        vq_main_fb<<<NROWS / 128, 128, 0, stream>>>(z, emb, eTe, out, loss_slot, loss_scale);
    }
}